// Round 4
// baseline (255.732 us; speedup 1.0000x reference)
//
#include <hip/hip_runtime.h>

typedef unsigned short u16;
typedef unsigned int u32;
typedef __attribute__((ext_vector_type(4))) float f32x4;
typedef __attribute__((ext_vector_type(8))) short bf16x8;
typedef __attribute__((ext_vector_type(4))) u32 u32x4;

__device__ __forceinline__ u16 f2bf(float f) {
  union { float f; u32 u; } v; v.f = f;
  u32 r = v.u + 0x7fffu + ((v.u >> 16) & 1u);
  return (u16)(r >> 16);
}

__device__ __forceinline__ void gload_lds16(const u16* g, u16* l) {
  __builtin_amdgcn_global_load_lds((__attribute__((address_space(1))) const void*)g,
                                   (__attribute__((address_space(3))) void*)l,
                                   16, 0, 0);
}

// ---------------- convert x (fp32 -> bf16), vectorized ----------------
__global__ void k_convert_x(const float4* __restrict__ in, uint2* __restrict__ out, int n4) {
  int i = blockIdx.x * blockDim.x + threadIdx.x;
  int stride = gridDim.x * blockDim.x;
  for (; i < n4; i += stride) {
    float4 v = in[i];
    u32 lo = (u32)f2bf(v.x) | ((u32)f2bf(v.y) << 16);
    u32 hi = (u32)f2bf(v.z) | ((u32)f2bf(v.w) << 16);
    out[i] = make_uint2(lo, hi);
  }
}

// ---------------- LDS-tiled transpose+convert: W (K x Nc) fp32 -> Wt (Nc x K) bf16 ----------------
__global__ void __launch_bounds__(256) k_transpose_w(const float* __restrict__ W,
                                                     u16* __restrict__ Wt, int K, int Nc) {
  __shared__ u16 t[64][72];  // [k][n], +8 pad
  const int tid = threadIdx.x;
  const int kb = blockIdx.x * 64, nb = blockIdx.y * 64;
  const int c4 = (tid & 15) * 4;
  const int r0 = tid >> 4;
#pragma unroll
  for (int rr = 0; rr < 4; ++rr) {
    int r = rr * 16 + r0;
    float4 v = *(const float4*)(W + (size_t)(kb + r) * Nc + nb + c4);
    t[r][c4 + 0] = f2bf(v.x);
    t[r][c4 + 1] = f2bf(v.y);
    t[r][c4 + 2] = f2bf(v.z);
    t[r][c4 + 3] = f2bf(v.w);
  }
  __syncthreads();
  const int c8 = (tid & 7) * 8;
  const int rn = tid >> 3;
#pragma unroll
  for (int rr = 0; rr < 2; ++rr) {
    int n = rr * 32 + rn;
    u16 tmp[8];
#pragma unroll
    for (int j = 0; j < 8; ++j) tmp[j] = t[c8 + j][n];
    *(u32x4*)(Wt + (size_t)(nb + n) * K + kb + c8) = *(const u32x4*)tmp;
  }
}

// ---------------- mask -> bitmask table ----------------
__global__ void k_mask_bits(const int* __restrict__ mask, u32* __restrict__ mtab) {
  int idx = blockIdx.x * blockDim.x + threadIdx.x;
  if (idx >= 64 * 144 * 8) return;
  int wd = idx & 7;
  int r = idx >> 3;  // combined w*144 + row
  u32 bits = 0;
  if (wd < 5) {
    int base = r * 144 + wd * 32;
    int nmax = 144 - wd * 32;
    if (nmax > 32) nmax = 32;
    for (int b = 0; b < nmax; ++b) bits |= (mask[base + b] ? 1u : 0u) << b;
  }
  mtab[idx] = bits;
}

// ---------------- GEMM v3: 256x256 tile, BK=64, 8 waves, phase-split schedule ----------------
template <bool OUT_BF16>
__global__ void __launch_bounds__(512) k_gemm256(const u16* __restrict__ A,
                                                 const u16* __restrict__ Bt,
                                                 const float* __restrict__ bias,
                                                 void* __restrict__ D,
                                                 int Nc, int K, int NB) {
  __shared__ u16 As[2][256 * 64];
  __shared__ u16 Bs[2][256 * 64];
  const int tid = threadIdx.x;
  const int wave = tid >> 6, lane = tid & 63;
  const int wr = wave >> 2, wc = wave & 3;   // 2 x 4 wave grid
  const int l15 = lane & 15, g = lane >> 4;
  const int sx = l15 & 7;                    // read-side swizzle key (row & 7)
  const f32x4 fzero = {0.f, 0.f, 0.f, 0.f};

  // XCD-aware swizzle: 8 XCDs get contiguous chunks of the grid
  const int nwg = gridDim.x;
  const int cpx = nwg >> 3;
  const int swz = (blockIdx.x & 7) * cpx + (blockIdx.x >> 3);
  const int bm = swz / NB, bn = swz % NB;

  const u16* Ab = A + (size_t)bm * 256 * K;
  const u16* Bb = Bt + (size_t)bn * 256 * K;

  f32x4 acc[8][4];
#pragma unroll
  for (int m = 0; m < 8; ++m)
#pragma unroll
    for (int n = 0; n < 4; ++n) acc[m][n] = fzero;

  // stage one K-tile (A and B, 256 rows x 64 cols each) into buffer `buf`.
  // LDS dest linear; global source chunk (16B) index XORed with (row & 7).
  auto STAGE = [&](int buf, int ks) {
#pragma unroll
    for (int i = 0; i < 4; ++i) {
      int e = i * 512 + tid;
      int r = e >> 3, c = e & 7;
      gload_lds16(Ab + (size_t)r * K + ks + ((c ^ (r & 7)) << 3), &As[buf][e * 8]);
    }
#pragma unroll
    for (int i = 0; i < 4; ++i) {
      int e = i * 512 + tid;
      int r = e >> 3, c = e & 7;
      gload_lds16(Bb + (size_t)r * K + ks + ((c ^ (r & 7)) << 3), &Bs[buf][e * 8]);
    }
  };

  const int nt = K >> 6;
  STAGE(0, 0);
  asm volatile("s_waitcnt vmcnt(0)" ::: "memory");
  __syncthreads();

  int cur = 0;
  for (int t = 0; t < nt; ++t) {
    if (t + 1 < nt) STAGE(cur ^ 1, (t + 1) << 6);  // issue next-tile loads FIRST
#pragma unroll
    for (int q = 0; q < 4; ++q) {
      const int mh = q & 1, kk = q >> 1;
      const int cx = kk * 4 + g;  // logical 16B chunk of this fragment
      bf16x8 a[4], b[4];
#pragma unroll
      for (int m = 0; m < 4; ++m) {
        int r = wr * 128 + mh * 64 + m * 16 + l15;
        a[m] = *(const bf16x8*)(&As[cur][r * 64 + ((cx ^ sx) << 3)]);
      }
#pragma unroll
      for (int n = 0; n < 4; ++n) {
        int r = wc * 64 + n * 16 + l15;
        b[n] = *(const bf16x8*)(&Bs[cur][r * 64 + ((cx ^ sx) << 3)]);
      }
      __builtin_amdgcn_s_barrier();
      __builtin_amdgcn_s_setprio(1);
#pragma unroll
      for (int m = 0; m < 4; ++m)
#pragma unroll
        for (int n = 0; n < 4; ++n)
          acc[mh * 4 + m][n] =
              __builtin_amdgcn_mfma_f32_16x16x32_bf16(a[m], b[n], acc[mh * 4 + m][n], 0, 0, 0);
      __builtin_amdgcn_s_setprio(0);
      __builtin_amdgcn_s_barrier();
    }
    if (t + 1 < nt) {
      asm volatile("s_waitcnt vmcnt(0)" ::: "memory");  // next buf fully staged (this wave)
      __syncthreads();                                  // ... and all waves
    }
    cur ^= 1;
  }

  const int row0 = bm * 256 + wr * 128;
  const int col0 = bn * 256 + wc * 64;
#pragma unroll
  for (int m = 0; m < 8; ++m) {
#pragma unroll
    for (int n = 0; n < 4; ++n) {
      int col = col0 + n * 16 + l15;
      float bv = bias[col];
#pragma unroll
      for (int j = 0; j < 4; ++j) {
        int row = row0 + m * 16 + g * 4 + j;
        float v = acc[m][n][j] + bv;
        if constexpr (OUT_BF16)
          ((u16*)D)[(size_t)row * Nc + col] = f2bf(v);
        else
          ((float*)D)[(size_t)row * Nc + col] = v;
      }
    }
  }
}

// ---------------- Window attention (unchanged from round 3) ----------------
__global__ void __launch_bounds__(256) k_attn(const u16* __restrict__ qkv,
                                              const u32* __restrict__ mtab,
                                              u16* __restrict__ obuf) {
  __shared__ u16 k_s[144 * 40];      // [n][d] +8 pad
  __shared__ u16 vT_s[32 * 168];     // [d][k] k padded to 160 (+8)
  __shared__ u16 P_s[4][16 * 168];   // per-wave [q][k], k padded to 160 (+8)

  const int bh = blockIdx.x;
  const int bn = bh >> 4, h = bh & 15;
  const int wid = bn & 63;
  const int tid = threadIdx.x;
  const int wave = tid >> 6, lane = tid & 63;
  const int l15 = lane & 15, g = lane >> 4;
  const f32x4 fzero = {0.f, 0.f, 0.f, 0.f};

  const u16* base = qkv + (size_t)bn * 144 * 1536 + h * 32;

  for (int e = tid; e < 576; e += 256) {
    int n = e >> 2, c = e & 3;
    const u16* rowp = base + (size_t)n * 1536 + c * 8;
    u32x4 kv = *(const u32x4*)(rowp + 512);
    u32x4 vv = *(const u32x4*)(rowp + 1024);
    *(u32x4*)(k_s + n * 40 + c * 8) = kv;
#pragma unroll
    for (int t = 0; t < 4; ++t) {
      u32 w = vv[t];
      vT_s[(c * 8 + 2 * t) * 168 + n] = (u16)(w & 0xffffu);
      vT_s[(c * 8 + 2 * t + 1) * 168 + n] = (u16)(w >> 16);
    }
  }
  for (int e = tid; e < 512; e += 256) {
    int d = e >> 4, c = e & 15;
    vT_s[d * 168 + 144 + c] = 0;
  }
  __syncthreads();

  const float scale = 0.17677669529663687f;  // 1/sqrt(32)
  u16* Pw = &P_s[wave][0];

  for (int mt = wave; mt < 9; mt += 4) {
    u32 mw[4][5];
#pragma unroll
    for (int j = 0; j < 4; ++j) {
      int r = mt * 16 + g * 4 + j;
      const u32* mp = mtab + ((size_t)(wid * 144 + r) << 3);
#pragma unroll
      for (int wd = 0; wd < 5; ++wd) mw[j][wd] = mp[wd];
    }

    bf16x8 a = *(const bf16x8*)(base + (size_t)(mt * 16 + l15) * 1536 + g * 8);

    f32x4 accs[9];
#pragma unroll
    for (int nt = 0; nt < 9; ++nt) {
      bf16x8 b = *(const bf16x8*)(k_s + (nt * 16 + l15) * 40 + g * 8);
      accs[nt] = __builtin_amdgcn_mfma_f32_16x16x32_bf16(a, b, fzero, 0, 0, 0);
    }

    float rmax[4] = {-1e30f, -1e30f, -1e30f, -1e30f};
#pragma unroll
    for (int nt = 0; nt < 9; ++nt) {
      const int wd = nt >> 1;
      const int sh = (nt & 1) * 16;
#pragma unroll
      for (int j = 0; j < 4; ++j) {
        float x = accs[nt][j] * scale;
        u32 bit = (mw[j][wd] >> (sh + l15)) & 1u;
        x = bit ? x : -1e9f;
        accs[nt][j] = x;
        rmax[j] = fmaxf(rmax[j], x);
      }
    }
#pragma unroll
    for (int off = 1; off < 16; off <<= 1)
#pragma unroll
      for (int j = 0; j < 4; ++j)
        rmax[j] = fmaxf(rmax[j], __shfl_xor(rmax[j], off, 64));

    float rsum[4] = {0.f, 0.f, 0.f, 0.f};
#pragma unroll
    for (int nt = 0; nt < 9; ++nt)
#pragma unroll
      for (int j = 0; j < 4; ++j) {
        float p = __expf(accs[nt][j] - rmax[j]);
        accs[nt][j] = p;
        rsum[j] += p;
      }
#pragma unroll
    for (int off = 1; off < 16; off <<= 1)
#pragma unroll
      for (int j = 0; j < 4; ++j)
        rsum[j] += __shfl_xor(rsum[j], off, 64);
    float rinv[4];
#pragma unroll
    for (int j = 0; j < 4; ++j) rinv[j] = 1.f / rsum[j];

#pragma unroll
    for (int nt = 0; nt < 9; ++nt)
#pragma unroll
      for (int j = 0; j < 4; ++j)
        Pw[(g * 4 + j) * 168 + nt * 16 + l15] = f2bf(accs[nt][j] * rinv[j]);
#pragma unroll
    for (int j = 0; j < 4; ++j)
      Pw[(g * 4 + j) * 168 + 144 + l15] = 0;

    asm volatile("s_waitcnt lgkmcnt(0)" ::: "memory");
    __builtin_amdgcn_sched_barrier(0);

    f32x4 acco[2];
    acco[0] = fzero;
    acco[1] = fzero;
#pragma unroll
    for (int kk = 0; kk < 5; ++kk) {
      bf16x8 pa = *(const bf16x8*)(Pw + l15 * 168 + kk * 32 + g * 8);
#pragma unroll
      for (int nt2 = 0; nt2 < 2; ++nt2) {
        bf16x8 b = *(const bf16x8*)(vT_s + (nt2 * 16 + l15) * 168 + kk * 32 + g * 8);
        acco[nt2] = __builtin_amdgcn_mfma_f32_16x16x32_bf16(pa, b, acco[nt2], 0, 0, 0);
      }
    }
#pragma unroll
    for (int nt2 = 0; nt2 < 2; ++nt2)
#pragma unroll
      for (int j = 0; j < 4; ++j) {
        int r = mt * 16 + g * 4 + j;
        int d = nt2 * 16 + l15;
        obuf[((size_t)bn * 144 + r) * 512 + h * 32 + d] = f2bf(acco[nt2][j]);
      }
  }
}

extern "C" void kernel_launch(void* const* d_in, const int* in_sizes, int n_in,
                              void* d_out, int out_size, void* d_ws, size_t ws_size,
                              hipStream_t stream) {
  const float* x = (const float*)d_in[0];
  const int* mask = (const int*)d_in[1];
  const float* Wqkv = (const float*)d_in[2];
  const float* bqkv = (const float*)d_in[3];
  const float* Wproj = (const float*)d_in[4];
  const float* bproj = (const float*)d_in[5];
  float* out = (float*)d_out;

  char* ws = (char*)d_ws;
  u16* xb      = (u16*)(ws + 0);          //  37,748,736 B (dead after GEMM1; mtab aliases here)
  u16* wqkv_t  = (u16*)(ws + 37748736);   //   1,572,864 B
  u16* qkv     = (u16*)(ws + 39321600);   // 113,246,208 B
  u16* obuf    = (u16*)(ws + 152567808);  //  37,748,736 B
  u16* wproj_t = (u16*)(ws + 190316544);  //     524,288 B  (total 190,840,832)
  u32* mtab    = (u32*)(ws + 0);          //     294,912 B — aliases xb, written AFTER GEMM1

  // 1) convert x to bf16
  k_convert_x<<<2048, 256, 0, stream>>>((const float4*)x, (uint2*)xb, 18874368 / 4);
  // 2) transpose+convert weights (LDS-tiled)
  k_transpose_w<<<dim3(8, 24), 256, 0, stream>>>(Wqkv, wqkv_t, 512, 1536);
  k_transpose_w<<<dim3(8, 8), 256, 0, stream>>>(Wproj, wproj_t, 512, 512);
  // 3) qkv = x @ Wqkv + bqkv (bf16 out) — 144x6 = 864 blocks (864 % 8 == 0)
  k_gemm256<true><<<864, 512, 0, stream>>>(xb, wqkv_t, bqkv, qkv, 1536, 512, 6);
  // 4) mask -> bitmask table (into the now-dead xb region)
  k_mask_bits<<<288, 256, 0, stream>>>(mask, mtab);
  // 5) window attention
  k_attn<<<4096, 256, 0, stream>>>(qkv, mtab, obuf);
  // 6) out = O @ Wproj + bproj (fp32 out) — 144x2 = 288 blocks (288 % 8 == 0)
  k_gemm256<false><<<288, 512, 0, stream>>>(obuf, wproj_t, bproj, out, 512, 512, 2);
}

// Round 5
// 223.766 us; speedup vs baseline: 1.1429x; 1.1429x over previous
//
#include <hip/hip_runtime.h>

typedef unsigned short u16;
typedef unsigned int u32;
typedef __attribute__((ext_vector_type(4))) float f32x4;
typedef __attribute__((ext_vector_type(8))) short bf16x8;
typedef __attribute__((ext_vector_type(4))) u32 u32x4;

__device__ __forceinline__ u16 f2bf(float f) {
  union { float f; u32 u; } v; v.f = f;
  u32 r = v.u + 0x7fffu + ((v.u >> 16) & 1u);
  return (u16)(r >> 16);
}

__device__ __forceinline__ void gload_lds16(const u16* g, u16* l) {
  __builtin_amdgcn_global_load_lds((__attribute__((address_space(1))) const void*)g,
                                   (__attribute__((address_space(3))) void*)l,
                                   16, 0, 0);
}

// ---------------- LDS-tiled transpose+convert: W (K x Nc) fp32 -> Wt (Nc x K) bf16 ----------------
__global__ void __launch_bounds__(256) k_transpose_w(const float* __restrict__ W,
                                                     u16* __restrict__ Wt, int K, int Nc) {
  __shared__ u16 t[64][72];  // [k][n], +8 pad
  const int tid = threadIdx.x;
  const int kb = blockIdx.x * 64, nb = blockIdx.y * 64;
  const int c4 = (tid & 15) * 4;
  const int r0 = tid >> 4;
#pragma unroll
  for (int rr = 0; rr < 4; ++rr) {
    int r = rr * 16 + r0;
    float4 v = *(const float4*)(W + (size_t)(kb + r) * Nc + nb + c4);
    t[r][c4 + 0] = f2bf(v.x);
    t[r][c4 + 1] = f2bf(v.y);
    t[r][c4 + 2] = f2bf(v.z);
    t[r][c4 + 3] = f2bf(v.w);
  }
  __syncthreads();
  const int c8 = (tid & 7) * 8;
  const int rn = tid >> 3;
#pragma unroll
  for (int rr = 0; rr < 2; ++rr) {
    int n = rr * 32 + rn;
    u16 tmp[8];
#pragma unroll
    for (int j = 0; j < 8; ++j) tmp[j] = t[c8 + j][n];
    *(u32x4*)(Wt + (size_t)(nb + n) * K + kb + c8) = *(const u32x4*)tmp;
  }
}

// ---------------- mask -> bitmask table ----------------
__global__ void k_mask_bits(const int* __restrict__ mask, u32* __restrict__ mtab) {
  int idx = blockIdx.x * blockDim.x + threadIdx.x;
  if (idx >= 64 * 144 * 8) return;
  int wd = idx & 7;
  int r = idx >> 3;  // combined w*144 + row
  u32 bits = 0;
  if (wd < 5) {
    int base = r * 144 + wd * 32;
    int nmax = 144 - wd * 32;
    if (nmax > 32) nmax = 32;
    for (int b = 0; b < nmax; ++b) bits |= (mask[base + b] ? 1u : 0u) << b;
  }
  mtab[idx] = bits;
}

// ---------------- GEMM v4: m97-structure, 128x128 tile, BK=64, 4 waves, SINGLE 32KB buffer ----------------
// ~3-4 blocks/CU for inter-block latency hiding. Chunk-XOR swizzle (0 bank conflicts),
// XCD-aware block swizzle. Raw s_barrier + explicit waitcnt (keeps counted vmcnt alive).
// A_FP32: A read as fp32 and converted in-kernel (fuses the x->bf16 convert into GEMM1);
//         A prefetched to regs one K-tile ahead -> counted vmcnt(8) across COMPUTE.
// else:   A staged via global_load_lds like B.
template <bool OUT_BF16, bool A_FP32>
__global__ void __launch_bounds__(256) k_gemm(const void* __restrict__ Ap,
                                              const u16* __restrict__ Bt,
                                              const float* __restrict__ bias,
                                              void* __restrict__ D,
                                              int Nc, int K, int NB) {
  __shared__ u16 As[128 * 64];
  __shared__ u16 Bs[128 * 64];
  const int tid = threadIdx.x;
  const int wave = tid >> 6, lane = tid & 63;
  const int wr = wave >> 1, wc = wave & 1;
  const int l15 = lane & 15, g = lane >> 4;
  const int sx = l15 & 7;  // read-side chunk swizzle key
  const f32x4 fzero = {0.f, 0.f, 0.f, 0.f};

  // XCD-aware swizzle (grid % 8 == 0): consecutive swz share the A panel -> L2-local
  const int cpx = gridDim.x >> 3;
  const int swz = (blockIdx.x & 7) * cpx + (blockIdx.x >> 3);
  const int bm = swz / NB, bn = swz % NB;

  const u16* Bb = Bt + (size_t)bn * 128 * K;

  f32x4 acc[4][4];
#pragma unroll
  for (int m = 0; m < 4; ++m)
#pragma unroll
    for (int n = 0; n < 4; ++n) acc[m][n] = fzero;

  const int nt = K >> 6;

  // A_FP32 prefetch registers: 4 chunks x 8 floats
  f32x4 areg[4][2];

  auto A_LOAD = [&](int t) {
    if constexpr (A_FP32) {
      const float* Af = (const float*)Ap;
#pragma unroll
      for (int i = 0; i < 4; ++i) {
        int e = i * 256 + tid;
        int r = e >> 3, c = e & 7;
        int cs = c ^ (r & 7);
        const float* p = Af + (size_t)(bm * 128 + r) * K + (t << 6) + cs * 8;
        areg[i][0] = *(const f32x4*)(p);
        areg[i][1] = *(const f32x4*)(p + 4);
      }
    }
  };

  auto A_WRITE = [&]() {
    if constexpr (A_FP32) {
#pragma unroll
      for (int i = 0; i < 4; ++i) {
        int e = i * 256 + tid;
        u32 w0, w1, w2, w3;
        asm("v_cvt_pk_bf16_f32 %0, %1, %2" : "=v"(w0) : "v"(areg[i][0][0]), "v"(areg[i][0][1]));
        asm("v_cvt_pk_bf16_f32 %0, %1, %2" : "=v"(w1) : "v"(areg[i][0][2]), "v"(areg[i][0][3]));
        asm("v_cvt_pk_bf16_f32 %0, %1, %2" : "=v"(w2) : "v"(areg[i][1][0]), "v"(areg[i][1][1]));
        asm("v_cvt_pk_bf16_f32 %0, %1, %2" : "=v"(w3) : "v"(areg[i][1][2]), "v"(areg[i][1][3]));
        u32x4 wv = {w0, w1, w2, w3};
        *(u32x4*)(&As[e * 8]) = wv;
      }
    }
  };

  auto A_STAGE_G = [&](int t) {
    if constexpr (!A_FP32) {
      const u16* Ab = (const u16*)Ap + (size_t)bm * 128 * K;
#pragma unroll
      for (int i = 0; i < 4; ++i) {
        int e = i * 256 + tid;
        int r = e >> 3, c = e & 7;
        int cs = c ^ (r & 7);
        gload_lds16(Ab + (size_t)r * K + (t << 6) + (cs << 3), &As[e * 8]);
      }
    }
  };

  auto B_STAGE = [&](int t) {
#pragma unroll
    for (int i = 0; i < 4; ++i) {
      int e = i * 256 + tid;
      int r = e >> 3, c = e & 7;
      int cs = c ^ (r & 7);
      gload_lds16(Bb + (size_t)r * K + (t << 6) + (cs << 3), &Bs[e * 8]);
    }
  };

  auto COMPUTE = [&]() {
#pragma unroll
    for (int kk = 0; kk < 2; ++kk) {
      const int cx = ((kk * 4 + g) ^ sx) << 3;
      bf16x8 a[4], b[4];
#pragma unroll
      for (int m = 0; m < 4; ++m)
        a[m] = *(const bf16x8*)(&As[(wr * 64 + m * 16 + l15) * 64 + cx]);
#pragma unroll
      for (int n = 0; n < 4; ++n)
        b[n] = *(const bf16x8*)(&Bs[(wc * 64 + n * 16 + l15) * 64 + cx]);
#pragma unroll
      for (int m = 0; m < 4; ++m)
#pragma unroll
        for (int n = 0; n < 4; ++n)
          acc[m][n] = __builtin_amdgcn_mfma_f32_16x16x32_bf16(a[m], b[n], acc[m][n], 0, 0, 0);
    }
  };

  if constexpr (A_FP32) {
    A_LOAD(0);
    for (int t = 0; t < nt; ++t) {
      A_WRITE();      // consumes A regs of tile t (compiler waits their vmcnt)
      B_STAGE(t);     // 4 gload_lds
      if (t + 1 < nt) {
        A_LOAD(t + 1);  // 8 fp32 loads stay in flight across COMPUTE
        asm volatile("s_waitcnt vmcnt(8) lgkmcnt(0)" ::: "memory");
      } else {
        asm volatile("s_waitcnt vmcnt(0) lgkmcnt(0)" ::: "memory");
      }
      __builtin_amdgcn_sched_barrier(0);
      __builtin_amdgcn_s_barrier();
      __builtin_amdgcn_sched_barrier(0);
      COMPUTE();
      __builtin_amdgcn_sched_barrier(0);
      __builtin_amdgcn_s_barrier();
    }
  } else {
    for (int t = 0; t < nt; ++t) {
      A_STAGE_G(t);
      B_STAGE(t);
      asm volatile("s_waitcnt vmcnt(0)" ::: "memory");
      __builtin_amdgcn_sched_barrier(0);
      __builtin_amdgcn_s_barrier();
      __builtin_amdgcn_sched_barrier(0);
      COMPUTE();
      __builtin_amdgcn_sched_barrier(0);
      __builtin_amdgcn_s_barrier();
    }
  }

  const int row0 = bm * 128 + wr * 64;
  const int col0 = bn * 128 + wc * 64;
#pragma unroll
  for (int m = 0; m < 4; ++m) {
#pragma unroll
    for (int n = 0; n < 4; ++n) {
      int col = col0 + n * 16 + l15;
      float bv = bias[col];
#pragma unroll
      for (int j = 0; j < 4; ++j) {
        int row = row0 + m * 16 + g * 4 + j;
        float v = acc[m][n][j] + bv;
        if constexpr (OUT_BF16)
          ((u16*)D)[(size_t)row * Nc + col] = f2bf(v);
        else
          ((float*)D)[(size_t)row * Nc + col] = v;
      }
    }
  }
}

// ---------------- Window attention (unchanged) ----------------
__global__ void __launch_bounds__(256) k_attn(const u16* __restrict__ qkv,
                                              const u32* __restrict__ mtab,
                                              u16* __restrict__ obuf) {
  __shared__ u16 k_s[144 * 40];      // [n][d] +8 pad
  __shared__ u16 vT_s[32 * 168];     // [d][k] k padded to 160 (+8)
  __shared__ u16 P_s[4][16 * 168];   // per-wave [q][k], k padded to 160 (+8)

  const int bh = blockIdx.x;
  const int bn = bh >> 4, h = bh & 15;
  const int wid = bn & 63;
  const int tid = threadIdx.x;
  const int wave = tid >> 6, lane = tid & 63;
  const int l15 = lane & 15, g = lane >> 4;
  const f32x4 fzero = {0.f, 0.f, 0.f, 0.f};

  const u16* base = qkv + (size_t)bn * 144 * 1536 + h * 32;

  for (int e = tid; e < 576; e += 256) {
    int n = e >> 2, c = e & 3;
    const u16* rowp = base + (size_t)n * 1536 + c * 8;
    u32x4 kv = *(const u32x4*)(rowp + 512);
    u32x4 vv = *(const u32x4*)(rowp + 1024);
    *(u32x4*)(k_s + n * 40 + c * 8) = kv;
#pragma unroll
    for (int t = 0; t < 4; ++t) {
      u32 w = vv[t];
      vT_s[(c * 8 + 2 * t) * 168 + n] = (u16)(w & 0xffffu);
      vT_s[(c * 8 + 2 * t + 1) * 168 + n] = (u16)(w >> 16);
    }
  }
  for (int e = tid; e < 512; e += 256) {
    int d = e >> 4, c = e & 15;
    vT_s[d * 168 + 144 + c] = 0;
  }
  __syncthreads();

  const float scale = 0.17677669529663687f;  // 1/sqrt(32)
  u16* Pw = &P_s[wave][0];

  for (int mt = wave; mt < 9; mt += 4) {
    u32 mw[4][5];
#pragma unroll
    for (int j = 0; j < 4; ++j) {
      int r = mt * 16 + g * 4 + j;
      const u32* mp = mtab + ((size_t)(wid * 144 + r) << 3);
#pragma unroll
      for (int wd = 0; wd < 5; ++wd) mw[j][wd] = mp[wd];
    }

    bf16x8 a = *(const bf16x8*)(base + (size_t)(mt * 16 + l15) * 1536 + g * 8);

    f32x4 accs[9];
#pragma unroll
    for (int nt = 0; nt < 9; ++nt) {
      bf16x8 b = *(const bf16x8*)(k_s + (nt * 16 + l15) * 40 + g * 8);
      accs[nt] = __builtin_amdgcn_mfma_f32_16x16x32_bf16(a, b, fzero, 0, 0, 0);
    }

    float rmax[4] = {-1e30f, -1e30f, -1e30f, -1e30f};
#pragma unroll
    for (int nt = 0; nt < 9; ++nt) {
      const int wd = nt >> 1;
      const int sh = (nt & 1) * 16;
#pragma unroll
      for (int j = 0; j < 4; ++j) {
        float x = accs[nt][j] * scale;
        u32 bit = (mw[j][wd] >> (sh + l15)) & 1u;
        x = bit ? x : -1e9f;
        accs[nt][j] = x;
        rmax[j] = fmaxf(rmax[j], x);
      }
    }
#pragma unroll
    for (int off = 1; off < 16; off <<= 1)
#pragma unroll
      for (int j = 0; j < 4; ++j)
        rmax[j] = fmaxf(rmax[j], __shfl_xor(rmax[j], off, 64));

    float rsum[4] = {0.f, 0.f, 0.f, 0.f};
#pragma unroll
    for (int nt = 0; nt < 9; ++nt)
#pragma unroll
      for (int j = 0; j < 4; ++j) {
        float p = __expf(accs[nt][j] - rmax[j]);
        accs[nt][j] = p;
        rsum[j] += p;
      }
#pragma unroll
    for (int off = 1; off < 16; off <<= 1)
#pragma unroll
      for (int j = 0; j < 4; ++j)
        rsum[j] += __shfl_xor(rsum[j], off, 64);
    float rinv[4];
#pragma unroll
    for (int j = 0; j < 4; ++j) rinv[j] = 1.f / rsum[j];

#pragma unroll
    for (int nt = 0; nt < 9; ++nt)
#pragma unroll
      for (int j = 0; j < 4; ++j)
        Pw[(g * 4 + j) * 168 + nt * 16 + l15] = f2bf(accs[nt][j] * rinv[j]);
#pragma unroll
    for (int j = 0; j < 4; ++j)
      Pw[(g * 4 + j) * 168 + 144 + l15] = 0;

    asm volatile("s_waitcnt lgkmcnt(0)" ::: "memory");
    __builtin_amdgcn_sched_barrier(0);

    f32x4 acco[2];
    acco[0] = fzero;
    acco[1] = fzero;
#pragma unroll
    for (int kk = 0; kk < 5; ++kk) {
      bf16x8 pa = *(const bf16x8*)(Pw + l15 * 168 + kk * 32 + g * 8);
#pragma unroll
      for (int nt2 = 0; nt2 < 2; ++nt2) {
        bf16x8 b = *(const bf16x8*)(vT_s + (nt2 * 16 + l15) * 168 + kk * 32 + g * 8);
        acco[nt2] = __builtin_amdgcn_mfma_f32_16x16x32_bf16(pa, b, acco[nt2], 0, 0, 0);
      }
    }
#pragma unroll
    for (int nt2 = 0; nt2 < 2; ++nt2)
#pragma unroll
      for (int j = 0; j < 4; ++j) {
        int r = mt * 16 + g * 4 + j;
        int d = nt2 * 16 + l15;
        obuf[((size_t)bn * 144 + r) * 512 + h * 32 + d] = f2bf(acco[nt2][j]);
      }
  }
}

extern "C" void kernel_launch(void* const* d_in, const int* in_sizes, int n_in,
                              void* d_out, int out_size, void* d_ws, size_t ws_size,
                              hipStream_t stream) {
  const float* x = (const float*)d_in[0];
  const int* mask = (const int*)d_in[1];
  const float* Wqkv = (const float*)d_in[2];
  const float* bqkv = (const float*)d_in[3];
  const float* Wproj = (const float*)d_in[4];
  const float* bproj = (const float*)d_in[5];
  float* out = (float*)d_out;

  char* ws = (char*)d_ws;
  u32* mtab    = (u32*)(ws + 0);          //     294,912 B
  u16* wqkv_t  = (u16*)(ws + 294912);     //   1,572,864 B
  u16* qkv     = (u16*)(ws + 1867776);    // 113,246,208 B
  u16* obuf    = (u16*)(ws + 115113984);  //  37,748,736 B
  u16* wproj_t = (u16*)(ws + 152862720);  //     524,288 B  (total 153,387,008)

  // 1) transpose+convert weights (LDS-tiled)
  k_transpose_w<<<dim3(8, 24), 256, 0, stream>>>(Wqkv, wqkv_t, 512, 1536);
  k_transpose_w<<<dim3(8, 8), 256, 0, stream>>>(Wproj, wproj_t, 512, 512);
  // 2) mask -> bitmask table
  k_mask_bits<<<288, 256, 0, stream>>>(mask, mtab);
  // 3) qkv = x @ Wqkv + bqkv (bf16 out); A = fp32 x, converted in-kernel.
  //    grid 288x12 = 3456 (3456 % 8 == 0)
  k_gemm<true, true><<<3456, 256, 0, stream>>>(x, wqkv_t, bqkv, qkv, 1536, 512, 12);
  // 4) window attention
  k_attn<<<4096, 256, 0, stream>>>(qkv, mtab, obuf);
  // 5) out = O @ Wproj + bproj (fp32 out); grid 288x4 = 1152 (1152 % 8 == 0)
  k_gemm<false, false><<<1152, 256, 0, stream>>>(obuf, wproj_t, bproj, out, 512, 512, 4);
}

// Round 6
// 220.614 us; speedup vs baseline: 1.1592x; 1.0143x over previous
//
#include <hip/hip_runtime.h>

typedef unsigned short u16;
typedef unsigned int u32;
typedef __attribute__((ext_vector_type(4))) float f32x4;
typedef __attribute__((ext_vector_type(8))) short bf16x8;
typedef __attribute__((ext_vector_type(4))) u32 u32x4;

__device__ __forceinline__ u16 f2bf(float f) {
  union { float f; u32 u; } v; v.f = f;
  u32 r = v.u + 0x7fffu + ((v.u >> 16) & 1u);
  return (u16)(r >> 16);
}

__device__ __forceinline__ void gload_lds16(const u16* g, u16* l) {
  __builtin_amdgcn_global_load_lds((__attribute__((address_space(1))) const void*)g,
                                   (__attribute__((address_space(3))) void*)l,
                                   16, 0, 0);
}

// ---------------- LDS-tiled transpose+convert: W (K x Nc) fp32 -> Wt (Nc x K) bf16 ----------------
__global__ void __launch_bounds__(256) k_transpose_w(const float* __restrict__ W,
                                                     u16* __restrict__ Wt, int K, int Nc) {
  __shared__ u16 t[64][72];  // [k][n], +8 pad
  const int tid = threadIdx.x;
  const int kb = blockIdx.x * 64, nb = blockIdx.y * 64;
  const int c4 = (tid & 15) * 4;
  const int r0 = tid >> 4;
#pragma unroll
  for (int rr = 0; rr < 4; ++rr) {
    int r = rr * 16 + r0;
    float4 v = *(const float4*)(W + (size_t)(kb + r) * Nc + nb + c4);
    t[r][c4 + 0] = f2bf(v.x);
    t[r][c4 + 1] = f2bf(v.y);
    t[r][c4 + 2] = f2bf(v.z);
    t[r][c4 + 3] = f2bf(v.w);
  }
  __syncthreads();
  const int c8 = (tid & 7) * 8;
  const int rn = tid >> 3;
#pragma unroll
  for (int rr = 0; rr < 2; ++rr) {
    int n = rr * 32 + rn;
    u16 tmp[8];
#pragma unroll
    for (int j = 0; j < 8; ++j) tmp[j] = t[c8 + j][n];
    *(u32x4*)(Wt + (size_t)(nb + n) * K + kb + c8) = *(const u32x4*)tmp;
  }
}

// ---------------- mask -> bitmask table ----------------
__global__ void k_mask_bits(const int* __restrict__ mask, u32* __restrict__ mtab) {
  int idx = blockIdx.x * blockDim.x + threadIdx.x;
  if (idx >= 64 * 144 * 8) return;
  int wd = idx & 7;
  int r = idx >> 3;  // combined w*144 + row
  u32 bits = 0;
  if (wd < 5) {
    int base = r * 144 + wd * 32;
    int nmax = 144 - wd * 32;
    if (nmax > 32) nmax = 32;
    for (int b = 0; b < nmax; ++b) bits |= (mask[base + b] ? 1u : 0u) << b;
  }
  mtab[idx] = bits;
}

// ---------------- GEMM v5: 128x128 tile, BK=64, 4 waves ----------------
// All waits at iteration top target loads issued one FULL iteration earlier:
//   A: global fp32 (or bf16) -> regs (issued iter t-1) -> cvt_pk -> ds_write into
//      single padded As[128][68] (pad breaks read bank conflicts; write side is
//      consecutive-lane b128 = conflict-free). Legal to pad: As is ds_write-fed.
//   B: gload_lds, DOUBLE-buffered (issued iter t-1), chunk-XOR source swizzle.
// One vmcnt(0)+lgkmcnt(0) per iter, raw s_barrier (no compiler forced drains).
// LDS = 17,408 + 32,768 = 50,176 B -> 3 blocks/CU; launch_bounds(256,3).
template <bool OUT_BF16, bool A_FP32>
__global__ void __launch_bounds__(256, 3) k_gemm(const void* __restrict__ Ap,
                                                 const u16* __restrict__ Bt,
                                                 const float* __restrict__ bias,
                                                 void* __restrict__ D,
                                                 int Nc, int K, int NB) {
  __shared__ u16 As[128 * 68];      // row stride 68 u16 = 136 B (pad +4)
  __shared__ u16 Bs[2][128 * 64];   // linear dest, chunk-XOR swizzled source
  const int tid = threadIdx.x;
  const int wave = tid >> 6, lane = tid & 63;
  const int wr = wave >> 1, wc = wave & 1;
  const int l15 = lane & 15, g = lane >> 4;
  const int sx = l15 & 7;
  const f32x4 fzero = {0.f, 0.f, 0.f, 0.f};

  // XCD-aware swizzle (grid % 8 == 0)
  const int cpx = gridDim.x >> 3;
  const int swz = (blockIdx.x & 7) * cpx + (blockIdx.x >> 3);
  const int bm = swz / NB, bn = swz % NB;

  const u16* Bb = Bt + (size_t)bn * 128 * K;

  // per-thread staging coords: e = i*256+tid -> row e>>3, 16B-chunk e&7
  int rr[4], cc[4];
#pragma unroll
  for (int i = 0; i < 4; ++i) {
    int e = i * 256 + tid;
    rr[i] = e >> 3;
    cc[i] = e & 7;
  }

  f32x4 acc[4][4];
#pragma unroll
  for (int m = 0; m < 4; ++m)
#pragma unroll
    for (int n = 0; n < 4; ++n) acc[m][n] = fzero;

  f32x4 areg[8];   // A_FP32 staging regs (32 VGPR)
  u32x4 aregb[4];  // bf16 staging regs (16 VGPR)

  auto A_LOAD = [&](int ks) {
    if constexpr (A_FP32) {
      const float* Af = (const float*)Ap;
#pragma unroll
      for (int i = 0; i < 4; ++i) {
        const float* p = Af + (size_t)(bm * 128 + rr[i]) * K + ks + cc[i] * 8;
        areg[2 * i] = *(const f32x4*)(p);
        areg[2 * i + 1] = *(const f32x4*)(p + 4);
      }
    } else {
      const u16* Ab = (const u16*)Ap + (size_t)bm * 128 * K;
#pragma unroll
      for (int i = 0; i < 4; ++i)
        aregb[i] = *(const u32x4*)(Ab + (size_t)rr[i] * K + ks + cc[i] * 8);
    }
  };

  auto A_WRITE = [&]() {
#pragma unroll
    for (int i = 0; i < 4; ++i) {
      u32x4 wv;
      if constexpr (A_FP32) {
        u32 w0, w1, w2, w3;
        asm("v_cvt_pk_bf16_f32 %0, %1, %2" : "=v"(w0) : "v"(areg[2 * i][0]), "v"(areg[2 * i][1]));
        asm("v_cvt_pk_bf16_f32 %0, %1, %2" : "=v"(w1) : "v"(areg[2 * i][2]), "v"(areg[2 * i][3]));
        asm("v_cvt_pk_bf16_f32 %0, %1, %2" : "=v"(w2) : "v"(areg[2 * i + 1][0]), "v"(areg[2 * i + 1][1]));
        asm("v_cvt_pk_bf16_f32 %0, %1, %2" : "=v"(w3) : "v"(areg[2 * i + 1][2]), "v"(areg[2 * i + 1][3]));
        wv[0] = w0; wv[1] = w1; wv[2] = w2; wv[3] = w3;
      } else {
        wv = aregb[i];
      }
      *(u32x4*)(&As[rr[i] * 68 + cc[i] * 8]) = wv;
    }
  };

  auto B_STAGE = [&](int buf, int ks) {
#pragma unroll
    for (int i = 0; i < 4; ++i) {
      int cs = cc[i] ^ (rr[i] & 7);
      gload_lds16(Bb + (size_t)rr[i] * K + ks + (cs << 3), &Bs[buf][(i * 256 + tid) * 8]);
    }
  };

  auto COMPUTE = [&](int buf) {
#pragma unroll
    for (int kk = 0; kk < 2; ++kk) {
      bf16x8 a[4], b[4];
#pragma unroll
      for (int m = 0; m < 4; ++m)
        a[m] = *(const bf16x8*)(&As[(wr * 64 + m * 16 + l15) * 68 + (kk * 4 + g) * 8]);
#pragma unroll
      for (int n = 0; n < 4; ++n)
        b[n] = *(const bf16x8*)(&Bs[buf][(wc * 64 + n * 16 + l15) * 64 + (((kk * 4 + g) ^ sx) << 3)]);
#pragma unroll
      for (int m = 0; m < 4; ++m)
#pragma unroll
        for (int n = 0; n < 4; ++n)
          acc[m][n] = __builtin_amdgcn_mfma_f32_16x16x32_bf16(a[m], b[n], acc[m][n], 0, 0, 0);
    }
  };

  const int nt = K >> 6;
  A_LOAD(0);
  B_STAGE(0, 0);
  int cur = 0;
  for (int t = 0; t < nt; ++t) {
    // everything waited here was issued one full iteration ago
    asm volatile("s_waitcnt vmcnt(0)" ::: "memory");
    __builtin_amdgcn_sched_barrier(0);
    if (t + 1 < nt) B_STAGE(cur ^ 1, (t + 1) << 6);  // into the buffer COMPUTE(t-1) read (safe: past its barrier)
    A_WRITE();                                        // consumes A regs of tile t
    if (t + 1 < nt) A_LOAD((t + 1) << 6);             // reload A regs for t+1 (in flight across COMPUTE)
    asm volatile("s_waitcnt lgkmcnt(0)" ::: "memory"); // own ds_writes done
    __builtin_amdgcn_sched_barrier(0);
    __builtin_amdgcn_s_barrier();                      // all waves: As written, Bs[cur] landed
    __builtin_amdgcn_sched_barrier(0);
    COMPUTE(cur);
    __builtin_amdgcn_sched_barrier(0);
    if (t + 1 < nt) __builtin_amdgcn_s_barrier();      // As / Bs[cur] free for overwrite
    cur ^= 1;
  }

  const int row0 = bm * 128 + wr * 64;
  const int col0 = bn * 128 + wc * 64;
#pragma unroll
  for (int m = 0; m < 4; ++m) {
#pragma unroll
    for (int n = 0; n < 4; ++n) {
      int col = col0 + n * 16 + l15;
      float bv = bias[col];
#pragma unroll
      for (int j = 0; j < 4; ++j) {
        int row = row0 + m * 16 + g * 4 + j;
        float v = acc[m][n][j] + bv;
        if constexpr (OUT_BF16)
          ((u16*)D)[(size_t)row * Nc + col] = f2bf(v);
        else
          ((float*)D)[(size_t)row * Nc + col] = v;
      }
    }
  }
}

// ---------------- Window attention (unchanged) ----------------
__global__ void __launch_bounds__(256) k_attn(const u16* __restrict__ qkv,
                                              const u32* __restrict__ mtab,
                                              u16* __restrict__ obuf) {
  __shared__ u16 k_s[144 * 40];      // [n][d] +8 pad
  __shared__ u16 vT_s[32 * 168];     // [d][k] k padded to 160 (+8)
  __shared__ u16 P_s[4][16 * 168];   // per-wave [q][k], k padded to 160 (+8)

  const int bh = blockIdx.x;
  const int bn = bh >> 4, h = bh & 15;
  const int wid = bn & 63;
  const int tid = threadIdx.x;
  const int wave = tid >> 6, lane = tid & 63;
  const int l15 = lane & 15, g = lane >> 4;
  const f32x4 fzero = {0.f, 0.f, 0.f, 0.f};

  const u16* base = qkv + (size_t)bn * 144 * 1536 + h * 32;

  for (int e = tid; e < 576; e += 256) {
    int n = e >> 2, c = e & 3;
    const u16* rowp = base + (size_t)n * 1536 + c * 8;
    u32x4 kv = *(const u32x4*)(rowp + 512);
    u32x4 vv = *(const u32x4*)(rowp + 1024);
    *(u32x4*)(k_s + n * 40 + c * 8) = kv;
#pragma unroll
    for (int t = 0; t < 4; ++t) {
      u32 w = vv[t];
      vT_s[(c * 8 + 2 * t) * 168 + n] = (u16)(w & 0xffffu);
      vT_s[(c * 8 + 2 * t + 1) * 168 + n] = (u16)(w >> 16);
    }
  }
  for (int e = tid; e < 512; e += 256) {
    int d = e >> 4, c = e & 15;
    vT_s[d * 168 + 144 + c] = 0;
  }
  __syncthreads();

  const float scale = 0.17677669529663687f;  // 1/sqrt(32)
  u16* Pw = &P_s[wave][0];

  for (int mt = wave; mt < 9; mt += 4) {
    u32 mw[4][5];
#pragma unroll
    for (int j = 0; j < 4; ++j) {
      int r = mt * 16 + g * 4 + j;
      const u32* mp = mtab + ((size_t)(wid * 144 + r) << 3);
#pragma unroll
      for (int wd = 0; wd < 5; ++wd) mw[j][wd] = mp[wd];
    }

    bf16x8 a = *(const bf16x8*)(base + (size_t)(mt * 16 + l15) * 1536 + g * 8);

    f32x4 accs[9];
#pragma unroll
    for (int nt = 0; nt < 9; ++nt) {
      bf16x8 b = *(const bf16x8*)(k_s + (nt * 16 + l15) * 40 + g * 8);
      accs[nt] = __builtin_amdgcn_mfma_f32_16x16x32_bf16(a, b, fzero, 0, 0, 0);
    }

    float rmax[4] = {-1e30f, -1e30f, -1e30f, -1e30f};
#pragma unroll
    for (int nt = 0; nt < 9; ++nt) {
      const int wd = nt >> 1;
      const int sh = (nt & 1) * 16;
#pragma unroll
      for (int j = 0; j < 4; ++j) {
        float x = accs[nt][j] * scale;
        u32 bit = (mw[j][wd] >> (sh + l15)) & 1u;
        x = bit ? x : -1e9f;
        accs[nt][j] = x;
        rmax[j] = fmaxf(rmax[j], x);
      }
    }
#pragma unroll
    for (int off = 1; off < 16; off <<= 1)
#pragma unroll
      for (int j = 0; j < 4; ++j)
        rmax[j] = fmaxf(rmax[j], __shfl_xor(rmax[j], off, 64));

    float rsum[4] = {0.f, 0.f, 0.f, 0.f};
#pragma unroll
    for (int nt = 0; nt < 9; ++nt)
#pragma unroll
      for (int j = 0; j < 4; ++j) {
        float p = __expf(accs[nt][j] - rmax[j]);
        accs[nt][j] = p;
        rsum[j] += p;
      }
#pragma unroll
    for (int off = 1; off < 16; off <<= 1)
#pragma unroll
      for (int j = 0; j < 4; ++j)
        rsum[j] += __shfl_xor(rsum[j], off, 64);
    float rinv[4];
#pragma unroll
    for (int j = 0; j < 4; ++j) rinv[j] = 1.f / rsum[j];

#pragma unroll
    for (int nt = 0; nt < 9; ++nt)
#pragma unroll
      for (int j = 0; j < 4; ++j)
        Pw[(g * 4 + j) * 168 + nt * 16 + l15] = f2bf(accs[nt][j] * rinv[j]);
#pragma unroll
    for (int j = 0; j < 4; ++j)
      Pw[(g * 4 + j) * 168 + 144 + l15] = 0;

    asm volatile("s_waitcnt lgkmcnt(0)" ::: "memory");
    __builtin_amdgcn_sched_barrier(0);

    f32x4 acco[2];
    acco[0] = fzero;
    acco[1] = fzero;
#pragma unroll
    for (int kk = 0; kk < 5; ++kk) {
      bf16x8 pa = *(const bf16x8*)(Pw + l15 * 168 + kk * 32 + g * 8);
#pragma unroll
      for (int nt2 = 0; nt2 < 2; ++nt2) {
        bf16x8 b = *(const bf16x8*)(vT_s + (nt2 * 16 + l15) * 168 + kk * 32 + g * 8);
        acco[nt2] = __builtin_amdgcn_mfma_f32_16x16x32_bf16(pa, b, acco[nt2], 0, 0, 0);
      }
    }
#pragma unroll
    for (int nt2 = 0; nt2 < 2; ++nt2)
#pragma unroll
      for (int j = 0; j < 4; ++j) {
        int r = mt * 16 + g * 4 + j;
        int d = nt2 * 16 + l15;
        obuf[((size_t)bn * 144 + r) * 512 + h * 32 + d] = f2bf(acco[nt2][j]);
      }
  }
}

extern "C" void kernel_launch(void* const* d_in, const int* in_sizes, int n_in,
                              void* d_out, int out_size, void* d_ws, size_t ws_size,
                              hipStream_t stream) {
  const float* x = (const float*)d_in[0];
  const int* mask = (const int*)d_in[1];
  const float* Wqkv = (const float*)d_in[2];
  const float* bqkv = (const float*)d_in[3];
  const float* Wproj = (const float*)d_in[4];
  const float* bproj = (const float*)d_in[5];
  float* out = (float*)d_out;

  char* ws = (char*)d_ws;
  u32* mtab    = (u32*)(ws + 0);          //     294,912 B
  u16* wqkv_t  = (u16*)(ws + 294912);     //   1,572,864 B
  u16* qkv     = (u16*)(ws + 1867776);    // 113,246,208 B
  u16* obuf    = (u16*)(ws + 115113984);  //  37,748,736 B
  u16* wproj_t = (u16*)(ws + 152862720);  //     524,288 B  (total 153,387,008)

  // 1) transpose+convert weights (LDS-tiled)
  k_transpose_w<<<dim3(8, 24), 256, 0, stream>>>(Wqkv, wqkv_t, 512, 1536);
  k_transpose_w<<<dim3(8, 8), 256, 0, stream>>>(Wproj, wproj_t, 512, 512);
  // 2) mask -> bitmask table
  k_mask_bits<<<288, 256, 0, stream>>>(mask, mtab);
  // 3) qkv = x @ Wqkv + bqkv (bf16 out); A = fp32 x converted in-kernel.
  //    grid 288x12 = 3456 (3456 % 8 == 0)
  k_gemm<true, true><<<3456, 256, 0, stream>>>(x, wqkv_t, bqkv, qkv, 1536, 512, 12);
  // 4) window attention
  k_attn<<<4096, 256, 0, stream>>>(qkv, mtab, obuf);
  // 5) out = O @ Wproj + bproj (fp32 out); grid 288x4 = 1152 (1152 % 8 == 0)
  k_gemm<false, false><<<1152, 256, 0, stream>>>(obuf, wproj_t, bproj, out, 512, 512, 4);
}